// Round 18
// baseline (316.113 us; speedup 1.0000x reference)
//
#include <hip/hip_runtime.h>
#include <stdint.h>

typedef unsigned short u16;
typedef unsigned int   u32;
typedef unsigned long long u64;
typedef __attribute__((ext_vector_type(8))) short short8;
typedef __attribute__((ext_vector_type(4))) short s16x4;
typedef __attribute__((ext_vector_type(4))) float f32x4;

#define B_    8
#define S_    1024
#define HID_  1024
#define NH_   16
#define HD_   64
#define E_    8
#define IDIM_ 128
#define NTOK  (B_*NH_*S_)   /* 131072 */

// padded-counter stride: one 64B cacheline per expert
#define CSTRIDE 16
// padded LDS row stride in floats (65 -> (row+d)%32 bank pattern, 2-way max)
#define XROW 65

// ---------- helpers ----------
__device__ __forceinline__ float bf2f(u16 u){ return __uint_as_float(((u32)u) << 16); }
__device__ __forceinline__ u16 f2bf(float f){
    u32 u = __float_as_uint(f);
    u32 r = u + 0x7fffu + ((u >> 16) & 1u);   // RNE
    return (u16)(r >> 16);
}
// 8 consecutive fp32 -> bf16 MFMA fragment (A or B operand)
__device__ __forceinline__ short8 frag8(const float* __restrict__ p){
    float4 a = *(const float4*)p;
    float4 b = *(const float4*)(p + 4);
    short8 r;
    r[0]=(short)f2bf(a.x); r[1]=(short)f2bf(a.y); r[2]=(short)f2bf(a.z); r[3]=(short)f2bf(a.w);
    r[4]=(short)f2bf(b.x); r[5]=(short)f2bf(b.y); r[6]=(short)f2bf(b.z); r[7]=(short)f2bf(b.w);
    return r;
}
// exact gelu (kept for scalar fallback path)
__device__ __forceinline__ float gelu_exact(float x){
    return 0.5f * x * (1.0f + erff(x * 0.70710678118654752f));
}
// tanh-form gelu: max abs err ~3e-4 vs exact; short dep chain, uses v_exp_f32
__device__ __forceinline__ float gelu_f(float x){
    float z = 1.5957691216057308f * (x + 0.044715f * x * x * x);   // 2*sqrt(2/pi)*(...)
    float e = __expf(z);                                            // exp(2*z_tanh)
    float t = 1.0f - 2.0f / (e + 1.0f);                             // tanh
    return 0.5f * x * (1.0f + t);
}

// ---------------- kernel 0: zero padded counters (fallback path only) ----------------
__global__ void k_zero(u32* c){
    c[threadIdx.x] = 0;   // launched with 256 threads
}

// ---------------- kernel 1 (fused): K/V/Q projections + memory cell + GATE + LN1/gelu ----------------
// Grid 512, 64 tokens/wave. writeXg=1: gate fused; bf16 xg rows go to the WS xg buffer
// (n-order, contiguous 16KB/wave). Per-block expert histogram -> pc[block][8] (plain
// stores). LESSONS (r13-r15): no tile time-sharing (spills); occupancy not the lever.
__global__ __launch_bounds__(256,2) void k_proj(
    const float* __restrict__ qin, const float* __restrict__ kin, const float* __restrict__ vin,
    const float* __restrict__ mem,
    const float* __restrict__ Wq, const float* __restrict__ Wk, const float* __restrict__ Wv,
    const float* __restrict__ fg,
    const float* __restrict__ gW, const float* __restrict__ gB,
    const float* __restrict__ l1g, const float* __restrict__ l1b,
    float* __restrict__ cur_out, float* __restrict__ out0, u16* __restrict__ xg,
    uint4* __restrict__ topiv, u32* __restrict__ pcount, int writeXg)
{
    __shared__ float sT[4][64*XROW];              // 66,560B: wave-private x tiles
    __shared__ float sGW[512], sGB[8];
    __shared__ float sG1[8*XROW], sB1g[8*XROW];   // stride-65: per-lane expert indexing conflict-free
    __shared__ u32 sWc1[4][8], sWc2[4][8];

    const int tid  = threadIdx.x;
    const int lane = tid & 63;
    const int wid  = tid >> 6;
    const int m    = lane & 15;
    const int kg   = lane >> 4;

    // stage gate/LN1 params (used only after the pre-epilogue barrier)
    for (int i = tid; i < 512; i += 256){
        sGW[i] = gW[i];
        const int e = i >> 6, d = i & 63;
        sG1[e*XROW+d] = l1g[i]; sB1g[e*XROW+d] = l1b[i];
    }
    if (tid < 8) sGB[tid] = gB[tid];

    const int slab  = blockIdx.x;                 // grid 512; slab == n-chunk index
    const int chunk = slab & 3, h = (slab >> 2) & 15, b = slab >> 6;
    const int tw    = chunk*256 + wid*64;         // 64 tokens per wave

    float* sW = &sT[wid][0];

    const float* kbase = kin + ((size_t)b*S_)*HID_ + h*64;
    const float* vbase = vin + ((size_t)b*S_)*HID_ + h*64;
    const float* qbase = qin + ((size_t)b*S_)*HID_ + h*64;

    f32x4 accK[4][4], accV[4][4];
    const f32x4 z = {0.f,0.f,0.f,0.f};
    #pragma unroll
    for (int i=0;i<4;i++){ accK[i][0]=z;accK[i][1]=z;accK[i][2]=z;accK[i][3]=z;
                           accV[i][0]=z;accV[i][1]=z;accV[i][2]=z;accV[i][3]=z; }

    // ---- K projection ----
    #pragma unroll
    for (int kk=0; kk<2; kk++){
        const int k0 = kk*32 + kg*8;
        short8 aF[4], bF[4];
        #pragma unroll
        for (int mt=0; mt<4; mt++) aF[mt] = frag8(kbase + (size_t)(tw + mt*16 + m)*HID_ + k0);
        #pragma unroll
        for (int ct=0; ct<4; ct++) bF[ct] = frag8(Wk + (ct*16 + m)*64 + k0);
        #pragma unroll
        for (int mt=0; mt<4; mt++)
            #pragma unroll
            for (int ct=0; ct<4; ct++)
                accK[mt][ct] = __builtin_amdgcn_mfma_f32_16x16x32_bf16(aF[mt], bF[ct], accK[mt][ct], 0,0,0);
    }
    // ---- V projection ----
    #pragma unroll
    for (int kk=0; kk<2; kk++){
        const int k0 = kk*32 + kg*8;
        short8 aF[4], bF[4];
        #pragma unroll
        for (int mt=0; mt<4; mt++) aF[mt] = frag8(vbase + (size_t)(tw + mt*16 + m)*HID_ + k0);
        #pragma unroll
        for (int ct=0; ct<4; ct++) bF[ct] = frag8(Wv + (ct*16 + m)*64 + k0);
        #pragma unroll
        for (int mt=0; mt<4; mt++)
            #pragma unroll
            for (int ct=0; ct<4; ct++)
                accV[mt][ct] = __builtin_amdgcn_mfma_f32_16x16x32_bf16(aF[mt], bF[ct], accV[mt][ct], 0,0,0);
    }

    const size_t nb = ((size_t)(b*NH_ + h)) << 10;
    float fgv[4];
    #pragma unroll
    for (int ct=0; ct<4; ct++) fgv[ct] = fg[ct*16 + m];

    // ---- epilogue 1: cell/cur -> out1; keep cur in accK ----
    #pragma unroll
    for (int mt=0; mt<4; mt++){
        #pragma unroll
        for (int r=0; r<4; r++){
            const int tok = tw + mt*16 + kg*4 + r;
            const size_t rowo = (nb + (size_t)tok)*64;
            #pragma unroll
            for (int ct=0; ct<4; ct++){
                const int d = ct*16 + m;
                const float kd = accK[mt][ct][r];
                const float vd = accV[mt][ct][r];
                const float f  = fgv[ct];
                const float mv = mem[rowo + d];
                const float cell = kd*vd + f*mv;
                const float cur  = (1.0f - f)*cell + f*mv;
                accK[mt][ct][r] = cur;            // keep for Q epilogue
                cur_out[rowo + d] = cur;
            }
        }
    }

    // ---- Q projection ----
    f32x4 accQ[4][4];
    #pragma unroll
    for (int i=0;i<4;i++){ accQ[i][0]=z;accQ[i][1]=z;accQ[i][2]=z;accQ[i][3]=z; }

    #pragma unroll
    for (int kk=0; kk<2; kk++){
        const int k0 = kk*32 + kg*8;
        short8 aF[4], bF[4];
        #pragma unroll
        for (int mt=0; mt<4; mt++) aF[mt] = frag8(qbase + (size_t)(tw + mt*16 + m)*HID_ + k0);
        #pragma unroll
        for (int ct=0; ct<4; ct++) bF[ct] = frag8(Wq + (ct*16 + m)*64 + k0);
        #pragma unroll
        for (int mt=0; mt<4; mt++)
            #pragma unroll
            for (int ct=0; ct<4; ct++)
                accQ[mt][ct] = __builtin_amdgcn_mfma_f32_16x16x32_bf16(aF[mt], bF[ct], accQ[mt][ct], 0,0,0);
    }

    if (!writeXg){
        // ---- fallback: fp32 x to out0 in pos-order (old k_gate computes gate later) ----
        #pragma unroll
        for (int mt=0; mt<4; mt++){
            #pragma unroll
            for (int r=0; r<4; r++){
                const int tok = tw + mt*16 + kg*4 + r;
                const size_t po = ((size_t)(b*S_ + tok)*NH_ + h)*64;
                #pragma unroll
                for (int ct=0; ct<4; ct++){
                    const int d = ct*16 + m;
                    out0[po + d] = accQ[mt][ct][r] * accK[mt][ct][r];
                }
            }
        }
        return;
    }

    __syncthreads();   // params staged; safe before first sGW use

    // ---- epilogue 2a: scatter x into wave tile (stride-65 rows) ----
    #pragma unroll
    for (int mt=0; mt<4; mt++){
        #pragma unroll
        for (int r=0; r<4; r++){
            const int trow = mt*16 + kg*4 + r;
            #pragma unroll
            for (int ct=0; ct<4; ct++){
                const int d = ct*16 + m;
                sW[trow*XROW + d] = accQ[mt][ct][r] * accK[mt][ct][r];
            }
        }
    }
    // in-wave DS ordering: lane's row reads below observe all wave writes above

    // ---- epilogue 2b: LANE = TOKEN — own row -> regs ((lane+d)%32 banks: 2-way) ----
    const int tok = tw + lane;
    const int n   = (int)(nb + tok);              // n-order index
    float rx[64];
    {
        const float* xr = &sW[lane*XROW];
        #pragma unroll
        for (int d = 0; d < 64; d++) rx[d] = xr[d];
    }

    // ---- epilogue 2c: logits + top-2 ----
    float lg[8];
    #pragma unroll
    for (int e = 0; e < 8; e++) lg[e] = sGB[e];
    float s0 = 0.f, s1 = 0.f;
    #pragma unroll
    for (int d = 0; d < 64; d++){
        const float xv = rx[d];
        s0 += xv; s1 += xv*xv;
        #pragma unroll
        for (int e = 0; e < 8; e++) lg[e] += sGW[e*64 + d] * xv;
    }

    int i1 = 0; float v1 = lg[0];
    #pragma unroll
    for (int e = 1; e < 8; e++){ if (lg[e] > v1){ v1 = lg[e]; i1 = e; } }
    int i2 = -1; float v2 = -3.0e38f;
    #pragma unroll
    for (int e = 0; e < 8; e++){ if (e != i1 && lg[e] > v2){ v2 = lg[e]; i2 = e; } }

    topiv[n] = make_uint4((u32)i1, (u32)i2, __float_as_uint(v1), __float_as_uint(v2));

    // per-wave expert histograms
    #pragma unroll
    for (int e = 0; e < 8; e++){
        u64 m1 = __ballot(i1 == e);
        u64 m2 = __ballot(i2 == e);
        if (lane == 0){ sWc1[wid][e] = (u32)__popcll(m1); sWc2[wid][e] = (u32)__popcll(m2); }
    }

    // ---- epilogue 2d: LN1 + gelu for both experts -> packed bf16 into OWN LDS row ----
    {
        const float mu = s0 * (1.0f/64.0f);
        const float rs = rsqrtf(s1 * (1.0f/64.0f) - mu*mu + 1e-5f);
        u32* xw = (u32*)&sW[lane*XROW];           // 64 u32 = 256B fits in 260B row
        #pragma unroll
        for (int half = 0; half < 2; half++){
            const int ee = half ? i2 : i1;
            const float* g1 = &sG1[ee*XROW];
            const float* b1 = &sB1g[ee*XROW];
            #pragma unroll
            for (int dp = 0; dp < 32; dp++){
                const float v0 = gelu_f((rx[2*dp+0] - mu)*rs*g1[2*dp+0] + b1[2*dp+0]);
                const float vb = gelu_f((rx[2*dp+1] - mu)*rs*g1[2*dp+1] + b1[2*dp+1]);
                xw[half*32 + dp] = (u32)f2bf(v0) | ((u32)f2bf(vb) << 16);
            }
        }
    }

    // ---- epilogue 2e: cooperative coalesced store — wave's 64 rows = contiguous 16KB ----
    {
        u16* xgbase = xg + ((nb + (size_t)tw) << 7);   // n-order, contiguous (WS buffer)
        #pragma unroll
        for (int j = 0; j < 16; j++){
            const int idx = j*64 + lane;          // uint4 index in [0,1024)
            const int row = idx >> 4, dc = idx & 15;
            const u32* p = (const u32*)&sW[row*XROW] + dc*4;
            uint4 v; v.x = p[0]; v.y = p[1]; v.z = p[2]; v.w = p[3];
            ((uint4*)xgbase)[idx] = v;
        }
    }

    __syncthreads();   // sWc complete across the 4 waves
    if (tid < 8){
        u32 t = sWc1[0][tid] + sWc1[1][tid] + sWc1[2][tid] + sWc1[3][tid]
              + sWc2[0][tid] + sWc2[1][tid] + sWc2[2][tid] + sWc2[3][tid];
        pcount[blockIdx.x*8 + tid] = t;           // plain store, incl. zero
    }
}

// ---------------- kernel 3 (fallback only): gate + top-2 — LDS-staged streamer ----------------
__global__ __launch_bounds__(256,2) void k_gate(
    float* __restrict__ x_io, const float* __restrict__ gW, const float* __restrict__ gB,
    const float* __restrict__ l1g, const float* __restrict__ l1b,
    uint4* __restrict__ topiv, u32* __restrict__ counts, int writeXg)
{
    __shared__ float sX[256*XROW];               // 66.6KB staged rows
    __shared__ float sGW[512], sGB[8];
    __shared__ float sG1[8*XROW], sB1g[8*XROW];
    __shared__ u32 sWc[4][8];

    const int tid = threadIdx.x;
    for (int i = tid; i < 512; i += 256){
        sGW[i] = gW[i];
        const int e = i >> 6, d = i & 63;
        sG1[e*XROW+d] = l1g[i]; sB1g[e*XROW+d] = l1b[i];
    }
    if (tid < 8) sGB[tid] = gB[tid];

    const int rowBase = blockIdx.x * 256;
    const float* gsrc = x_io + ((size_t)rowBase << 6);
    #pragma unroll
    for (int j = 0; j < 16; j++){
        const int idx = j*256 + tid;
        const int row = idx >> 4, dc = idx & 15;
        float4 v = ((const float4*)gsrc)[idx];
        float* p = &sX[row*XROW + dc*4];
        p[0]=v.x; p[1]=v.y; p[2]=v.z; p[3]=v.w;
    }
    __syncthreads();

    const int pos = rowBase + tid;
    const int h  = pos & (NH_-1);
    const int bs = pos >> 4;
    const int s  = bs & (S_-1), b = bs >> 10;
    const int n  = ((b*NH_ + h) << 10) + s;

    float rx[64];
    {
        const float* xr = &sX[tid*XROW];
        #pragma unroll
        for (int d = 0; d < 64; d++) rx[d] = xr[d];
    }

    float lg[8];
    #pragma unroll
    for (int e = 0; e < 8; e++) lg[e] = sGB[e];
    float s0 = 0.f, s1 = 0.f;
    #pragma unroll
    for (int d = 0; d < 64; d++){
        const float xv = rx[d];
        s0 += xv; s1 += xv*xv;
        #pragma unroll
        for (int e = 0; e < 8; e++) lg[e] += sGW[e*64 + d] * xv;
    }

    int i1 = 0; float v1 = lg[0];
    #pragma unroll
    for (int e = 1; e < 8; e++){ if (lg[e] > v1){ v1 = lg[e]; i1 = e; } }
    int i2 = -1; float v2 = -3.0e38f;
    #pragma unroll
    for (int e = 0; e < 8; e++){ if (e != i1 && lg[e] > v2){ v2 = lg[e]; i2 = e; } }

    topiv[n] = make_uint4((u32)i1, (u32)i2, __float_as_uint(v1), __float_as_uint(v2));

    {
        const int lane = tid & 63;
        const int w    = tid >> 6;
        #pragma unroll
        for (int e = 0; e < 8; e++){
            u64 m1 = __ballot(i1 == e);
            u64 m2 = __ballot(i2 == e);
            if (lane == 0) sWc[w][e] = (u32)(__popcll(m1) + __popcll(m2));
        }
    }
    __syncthreads();

    if (tid < 8){
        u32 t = sWc[0][tid] + sWc[1][tid] + sWc[2][tid] + sWc[3][tid];
        if (t) atomicAdd(&counts[tid*CSTRIDE], t);
    }
    (void)writeXg;
}

// ---------------- kernel 4: scatter + weight conversion + prefix + out0 zero (hot) ----------------
__global__ __launch_bounds__(256,2) void k_scatter(
    const uint4* __restrict__ topiv, u32* __restrict__ counts, u32* __restrict__ cursors,
    const u32* __restrict__ pc,
    const float* __restrict__ W1, const float* __restrict__ W2,
    u16* __restrict__ wB1, u16* __restrict__ wB2,
    u32* __restrict__ bucket, int2* __restrict__ slots, float* __restrict__ out0z,
    int useMfma)
{
    __shared__ u32 sC1[4][8], sC2[4][8];   // per-wave counts
    __shared__ u32 sB1[4][8], sB2w[4][8];  // per-wave slot bases (absolute)
    __shared__ u32 pcL[4096];              // 16KB pc table
    __shared__ u32 sTot[8], sBase[8];

    const int tid = threadIdx.x;
    const int j   = blockIdx.x;
    const int n   = j*256 + tid;

    if (useMfma){
        // weight conversion: exactly one element per thread across the grid
        if (n < 65536) wB1[n] = f2bf(W1[n]);
        else           wB2[n - 65536] = f2bf(W2[n - 65536]);
        for (int i = tid; i < 4096; i += 256) pcL[i] = pc[i];
        // zero out0 accumulator (expert atomically accumulates into it next)
        float4* zp = (float4*)out0z + (size_t)j*4096;
        const float4 z4 = {0.f,0.f,0.f,0.f};
        #pragma unroll
        for (int k = 0; k < 16; k++) zp[k*256 + tid] = z4;
    }

    uint4 t = topiv[n];
    const int i1 = (int)t.x, i2 = (int)t.y;

    const int lane = tid & 63;
    const int w    = tid >> 6;
    const u64 low = (1ull << lane) - 1ull;

    u64 myM1 = 0, myM2 = 0;
    #pragma unroll
    for (int e = 0; e < 8; e++){
        u64 m1 = __ballot(i1 == e);
        u64 m2 = __ballot(i2 == e);
        if (i1 == e) myM1 = m1;
        if (i2 == e) myM2 = m2;
        if (lane == 0){ sC1[w][e] = (u32)__popcll(m1); sC2[w][e] = (u32)__popcll(m2); }
    }
    __syncthreads();

    if (useMfma){
        if (tid < 8){
            const int e = tid;
            u32 tot = 0, base = 0;
            for (int i = 0; i < 512; i++){
                const u32 c = pcL[i*8 + e];
                tot += c;
                if (i < j) base += c;
            }
            sTot[e] = tot; sBase[e] = base;
            if (j == 0) counts[e*CSTRIDE] = tot;   // publish for expert
        }
        __syncthreads();
        if (tid < 8){
            const int e = tid;
            u32 off = 0;
            #pragma unroll
            for (int ee = 0; ee < 8; ee++){ if (ee < e) off += sTot[ee]; }
            u32 run = off + sBase[e];
            #pragma unroll
            for (int ww = 0; ww < 4; ww++){
                sB1[ww][e] = run; run += sC1[ww][e];
                sB2w[ww][e] = run; run += sC2[ww][e];
            }
        }
        __syncthreads();
    } else {
        int off[8]; int acc = 0;
        #pragma unroll
        for (int e = 0; e < 8; e++){ off[e] = acc; acc += (int)counts[e*CSTRIDE]; }
        if (tid < 8){
            const int e = tid;
            u32 tot = 0;
            #pragma unroll
            for (int ww = 0; ww < 4; ww++) tot += sC1[ww][e] + sC2[ww][e];
            u32 base = tot ? atomicAdd(&cursors[e*CSTRIDE], tot) : 0;
            u32 run = (u32)off[e] + base;
            #pragma unroll
            for (int ww = 0; ww < 4; ww++){
                sB1[ww][e] = run; run += sC1[ww][e];
                sB2w[ww][e] = run; run += sC2[ww][e];
            }
        }
        __syncthreads();
    }

    const int slot1 = (int)sB1[w][i1] + (int)__popcll(myM1 & low);
    const int slot2 = (int)sB2w[w][i2] + (int)__popcll(myM2 & low);

    bucket[slot1] = ((u32)n << 1);
    bucket[slot2] = ((u32)n << 1) | 1u;
    if (!useMfma) slots[n] = make_int2(slot1, slot2);   // hot path: slots region holds pc
}

// ---------------- kernel 5 (MFMA): expert FFN -> weighted fp32 atomic accumulate ----------------
// Each output element receives exactly TWO commutative fp32 adds onto 0 -> order-invariant.
__global__ __launch_bounds__(256,4) void k_expert_mfma(
    const u16* __restrict__ xg, const u32* __restrict__ bucket, const u32* __restrict__ counts,
    const uint4* __restrict__ topiv,
    const u16* __restrict__ wB1, const u16* __restrict__ wB2,
    const float* __restrict__ l2g, const float* __restrict__ l2b,
    const float* __restrict__ b2,  float* __restrict__ out0)
{
    const int e = blockIdx.x >> 10;
    const int c = blockIdx.x & 1023;
    const int cnt = (int)counts[e*CSTRIDE];
    const int aBase = c * 128;
    if (aBase >= cnt) return;     // block-uniform, before any barrier

    int off = 0;
    #pragma unroll
    for (int ee = 0; ee < 8; ee++){ if (ee < e) off += (int)counts[ee*CSTRIDE]; }

    __shared__ __align__(16) u16 sH[4][32*128];   // 8KB per wave (GEMM2 A transpose)
    __shared__ float sL2g[128], sL2b[128], sB2[64];

    const int tid = threadIdx.x;
    if (tid < 128){ sL2g[tid] = l2g[e*128+tid]; sL2b[tid] = l2b[e*128+tid]; }
    else if (tid < 192){ sB2[tid-128] = b2[e*64 + tid-128]; }
    __syncthreads();   // only barrier in the kernel

    const int lane = tid & 63;
    const int w    = tid >> 6;
    const int m    = lane & 15;
    const int kg   = lane >> 4;
    const int tb   = aBase + w*32;          // wave token base
    char* sHw = (char*)(&sH[w][0]);         // wave-private 8KB

    // ---- phase A: gather pre-staged bf16 A-rows (xg half-rows, n-order) ----
    short8 aF[2][2];   // [tile][kk]
    #pragma unroll
    for (int t = 0; t < 2; t++){
        int a = tb + t*16 + m; if (a > cnt-1) a = cnt-1;
        const u32 bv = bucket[off + a];
        const u16* rp = xg + (((size_t)(bv >> 1)) << 7) + (bv & 1u)*64;
        aF[t][0] = *(const short8*)(rp + kg*8);
        aF[t][1] = *(const short8*)(rp + 32 + kg*8);
    }

    // ---- GEMM1: H[32x128] = A1[32x64] @ W1^T ----
    const f32x4 z = {0.f,0.f,0.f,0.f};
    f32x4 acc1[2][8];
    #pragma unroll
    for (int t = 0; t < 2; t++)
        #pragma unroll
        for (int ct = 0; ct < 8; ct++) acc1[t][ct] = z;

    const u16* wB1e = wB1 + e*8192;
    #pragma unroll
    for (int kk = 0; kk < 2; kk++){
        const int k0 = kk*32 + kg*8;
        short8 bF[8];
        #pragma unroll
        for (int ct = 0; ct < 8; ct++)
            bF[ct] = *(const short8*)(wB1e + (ct*16 + m)*64 + k0);
        #pragma unroll
        for (int t = 0; t < 2; t++)
            #pragma unroll
            for (int ct = 0; ct < 8; ct++)
                acc1[t][ct] = __builtin_amdgcn_mfma_f32_16x16x32_bf16(aF[t][kk], bF[ct], acc1[t][ct], 0,0,0);
    }

    // ---- LN2 (reduce over m-lanes) + gelu -> wave-private sH (swizzled) ----
    #pragma unroll
    for (int t = 0; t < 2; t++){
        #pragma unroll
        for (int r = 0; r < 4; r++){
            float p0 = 0.f, p1 = 0.f;
            #pragma unroll
            for (int ct = 0; ct < 8; ct++){ float v = acc1[t][ct][r]; p0 += v; p1 += v*v; }
            #pragma unroll
            for (int msk = 1; msk < 16; msk <<= 1){
                p0 += __shfl_xor(p0, msk);
                p1 += __shfl_xor(p1, msk);
            }
            const float mu = p0 * (1.0f/128.0f);
            const float rs = rsqrtf(p1 * (1.0f/128.0f) - mu*mu + 1e-5f);
            const int row = t*16 + kg*4 + r;           // local row 0..31
            #pragma unroll
            for (int ct = 0; ct < 8; ct++){
                const int col = ct*16 + m;
                *(u16*)(sHw + (((row<<8) + (col<<1)) ^ ((row&7)<<4)))
                    = f2bf(gelu_f((acc1[t][ct][r] - mu)*rs*sL2g[col] + sL2b[col]));
            }
        }
    }
    // DS ops are in-order within a wave: reads below observe the writes above.

    // ---- GEMM2: OUT[32x64] = H[32x128] @ W2^T ----
    f32x4 acc2[2][4];
    #pragma unroll
    for (int t = 0; t < 2; t++)
        #pragma unroll
        for (int ct = 0; ct < 4; ct++) acc2[t][ct] = z;

    const u16* wB2e = wB2 + e*8192;
    #pragma unroll
    for (int kk = 0; kk < 4; kk++){
        const int k0 = kk*32 + kg*8;
        short8 aF2[2], bF2[4];
        #pragma unroll
        for (int t = 0; t < 2; t++){
            const int row = t*16 + m;
            aF2[t] = *(const short8*)(sHw + (((row<<8) + (k0<<1)) ^ ((row&7)<<4)));
        }
        #pragma unroll
        for (int ct = 0; ct < 4; ct++)
            bF2[ct] = *(const short8*)(wB2e + (ct*16 + m)*128 + k0);
        #pragma unroll
        for (int t = 0; t < 2; t++)
            #pragma unroll
            for (int ct = 0; ct < 4; ct++)
                acc2[t][ct] = __builtin_amdgcn_mfma_f32_16x16x32_bf16(aF2[t], bF2[ct], acc2[t][ct], 0,0,0);
    }

    // ---- epilogue: weighted fp32 atomic accumulate into out0 (pos-order) ----
    #pragma unroll
    for (int t = 0; t < 2; t++){
        #pragma unroll
        for (int r = 0; r < 4; r++){
            const int row = t*16 + kg*4 + r;
            const int gr  = tb + row;
            if (gr < cnt){
                const u32 bv = bucket[off + gr];          // broadcast across 16 m-lanes
                const u32 nn = bv >> 1;
                const uint4 tv = topiv[nn];
                const float wgt = __uint_as_float((bv & 1u) ? tv.w : tv.z);
                const int ss = (int)(nn & (S_-1));
                const int hh = (int)((nn >> 10) & (NH_-1));
                const int bb = (int)(nn >> 14);
                float* op = out0 + ((size_t)((bb*S_ + ss)*NH_ + hh) << 6);
                #pragma unroll
                for (int ct = 0; ct < 4; ct++){
                    const int col = ct*16 + m;
                    atomicAdd(&op[col], wgt*(acc2[t][ct][r] + sB2[col]));
                }
            }
        }
    }
}

// ---------------- kernel 5 (fallback, scalar — used only if ws too small; raw x intact) ----------------
__global__ __launch_bounds__(256,2) void k_expert(
    const float* __restrict__ x_src, const u32* __restrict__ bucket, const u32* __restrict__ counts,
    const float* __restrict__ W1,  const float* __restrict__ W2,
    const float* __restrict__ l1g, const float* __restrict__ l1b,
    const float* __restrict__ l2g, const float* __restrict__ l2b,
    const float* __restrict__ b2,  u16* __restrict__ aout)
{
    const int e = blockIdx.x >> 9;
    const int c = blockIdx.x & 511;
    const int cnt = (int)counts[e*CSTRIDE];
    const int aBase = c * 256;
    if (aBase >= cnt) return;

    int off = 0;
    for (int ee = 0; ee < 8; ee++){ if (ee < e) off += (int)counts[ee*CSTRIDE]; }

    __shared__ float sW1[8192];
    __shared__ float sW2T[128*68];
    __shared__ float sL1g[64], sL1b[64], sL2g[128], sL2b[128], sB2[64];
    const int tid = threadIdx.x;
    for (int i = tid; i < 8192; i += 256){
        sW1[i] = W1[e*8192 + i];
        int d = i >> 7, j = i & 127;
        sW2T[j*68 + d] = W2[e*8192 + i];
    }
    if (tid < 64){ sL1g[tid] = l1g[e*64+tid]; sL1b[tid] = l1b[e*64+tid]; sB2[tid] = b2[e*64+tid]; }
    if (tid < 128){ sL2g[tid] = l2g[e*128+tid]; sL2b[tid] = l2b[e*128+tid]; }
    __syncthreads();

    const int a = aBase + tid;
    if (a >= cnt) return;
    const u32 nv = bucket[off + a] >> 1;          // n-order index
    const int s = (int)(nv & (S_-1));
    const int h = (int)((nv >> 10) & (NH_-1));
    const int b = (int)(nv >> 14);
    const u32 pos32 = (u32)((b*S_ + s)*NH_ + h);

    float g[64];
    #pragma unroll
    for (int i = 0; i < 16; i++){
        float4 t = ((const float4*)(x_src + (size_t)pos32*64))[i];
        g[i*4+0]=t.x; g[i*4+1]=t.y; g[i*4+2]=t.z; g[i*4+3]=t.w;
    }

    float s0 = 0.f, s1 = 0.f;
    #pragma unroll
    for (int d = 0; d < 64; d++){ s0 += g[d]; s1 += g[d]*g[d]; }
    float m  = s0 * (1.0f/64.0f);
    float va = s1 * (1.0f/64.0f) - m*m;
    float rs = rsqrtf(va + 1e-5f);
    #pragma unroll
    for (int d = 0; d < 64; d++) g[d] = gelu_exact((g[d]-m)*rs*sL1g[d] + sL1b[d]);

    u32 hpk[64];
    float hs = 0.f, hs2 = 0.f;
    for (int jp = 0; jp < 64; jp++){
        float h0, h1;
        {
            float a0=0.f,a1=0.f,a2=0.f,a3=0.f;
            const float4* w4 = (const float4*)&sW1[(2*jp)*64];
            #pragma unroll
            for (int i = 0; i < 16; i++){
                float4 ww = w4[i];
                a0 += ww.x*g[i*4+0]; a1 += ww.y*g[i*4+1]; a2 += ww.z*g[i*4+2]; a3 += ww.w*g[i*4+3];
            }
            h0 = (a0+a1)+(a2+a3);
        }
        {
            float a0=0.f,a1=0.f,a2=0.f,a3=0.f;
            const float4* w4 = (const float4*)&sW1[(2*jp+1)*64];
            #pragma unroll
            for (int i = 0; i < 16; i++){
                float4 ww = w4[i];
                a0 += ww.x*g[i*4+0]; a1 += ww.y*g[i*4+1]; a2 += ww.z*g[i*4+2]; a3 += ww.w*g[i*4+3];
            }
            h1 = (a0+a1)+(a2+a3);
        }
        hs += h0 + h1; hs2 += h0*h0 + h1*h1;
        hpk[jp] = (u32)f2bf(h0) | ((u32)f2bf(h1) << 16);
    }
    float m2  = hs  * (1.0f/128.0f);
    float va2 = hs2 * (1.0f/128.0f) - m2*m2;
    float rs2 = rsqrtf(va2 + 1e-5f);

    float acc[64];
    #pragma unroll
    for (int d = 0; d < 64; d++) acc[d] = sB2[d];
    for (int j = 0; j < 128; j++){
        float hj = bf2f((u16)((j & 1) ? (hpk[j>>1] >> 16) : (hpk[j>>1] & 0xffffu)));
        float gh = gelu_exact((hj - m2)*rs2*sL2g[j] + sL2b[j]);
        const float4* w2t = (const float4*)&sW2T[j*68];
        #pragma unroll
        for (int d4 = 0; d4 < 16; d4++){
            float4 w = w2t[d4];
            acc[d4*4+0] += gh * w.x;
            acc[d4*4+1] += gh * w.y;
            acc[d4*4+2] += gh * w.z;
            acc[d4*4+3] += gh * w.w;
        }
    }

    u16* op = aout + (size_t)(off + a) * 64;
    #pragma unroll
    for (int dc = 0; dc < 8; dc++){
        uint4 o;
        o.x = (u32)f2bf(acc[dc*8+0]) | ((u32)f2bf(acc[dc*8+1]) << 16);
        o.y = (u32)f2bf(acc[dc*8+2]) | ((u32)f2bf(acc[dc*8+3]) << 16);
        o.z = (u32)f2bf(acc[dc*8+4]) | ((u32)f2bf(acc[dc*8+5]) << 16);
        o.w = (u32)f2bf(acc[dc*8+6]) | ((u32)f2bf(acc[dc*8+7]) << 16);
        ((uint4*)op)[dc] = o;
    }
}

// ---------------- kernel 6 (fallback only): combine top-2 expert outputs -> out0 ----------------
__global__ __launch_bounds__(256,4) void k_combine(
    const u16* __restrict__ aout, const uint4* __restrict__ topiv,
    const int2* __restrict__ slots, float* __restrict__ out0)
{
    const int tid = threadIdx.x;
    const int p   = blockIdx.x*16 + (tid >> 4);
    const int cq  = tid & 15;

    const int h  = p & (NH_-1);
    const int bs = p >> 4;
    const int b  = bs >> 10, s = bs & (S_-1);
    const int n  = ((b*NH_ + h) << 10) + s;

    uint4 t = topiv[n];
    float w1 = __uint_as_float(t.z), w2 = __uint_as_float(t.w);
    int2 sl = slots[n];

    uint2 ua = *(const uint2*)(aout + (size_t)sl.x*64 + cq*4);
    uint2 ub = *(const uint2*)(aout + (size_t)sl.y*64 + cq*4);

    float4 o;
    o.x = w1*bf2f((u16)(ua.x & 0xffffu)) + w2*bf2f((u16)(ub.x & 0xffffu));
    o.y = w1*bf2f((u16)(ua.x >> 16))     + w2*bf2f((u16)(ub.x >> 16));
    o.z = w1*bf2f((u16)(ua.y & 0xffffu)) + w2*bf2f((u16)(ub.y & 0xffffu));
    o.w = w1*bf2f((u16)(ua.y >> 16))     + w2*bf2f((u16)(ub.y >> 16));
    *(float4*)(out0 + (size_t)p*64 + cq*4) = o;
}

// ---------------- launch ----------------
extern "C" void kernel_launch(void* const* d_in, const int* in_sizes, int n_in,
                              void* d_out, int out_size, void* d_ws, size_t ws_size,
                              hipStream_t stream)
{
    const float* qin = (const float*)d_in[0];
    const float* kin = (const float*)d_in[1];
    const float* vin = (const float*)d_in[2];
    const float* mem = (const float*)d_in[3];
    const float* Wq  = (const float*)d_in[4];
    const float* Wk  = (const float*)d_in[5];
    const float* Wv  = (const float*)d_in[6];
    const float* fg  = (const float*)d_in[7];
    const float* gW  = (const float*)d_in[8];
    const float* gB  = (const float*)d_in[9];
    const float* l1g = (const float*)d_in[10];
    const float* l1b = (const float*)d_in[11];
    const float* W1  = (const float*)d_in[12];
    const float* l2g = (const float*)d_in[13];
    const float* l2b = (const float*)d_in[14];
    const float* W2  = (const float*)d_in[15];
    const float* b2  = (const float*)d_in[16];

    float* out0 = (float*)d_out;                    // token_mixing [B,S,NH*HD]
    float* out1 = out0 + (size_t)NTOK * 64;         // current_memorys [B,NH,S,HD]

    // ws layout (WS_NEED unchanged). Hot path: xg buffer occupies the aout region
    // (33.5MB, lifetime proj->expert); pc lives in the slots region (slots unused
    // in hot path — expert accumulates via atomics, no combine).
    char* ws = (char*)d_ws;
    u16*   aout   = (u16*)(ws);                               // 2N*64*2  = 33,554,432
    u16*   xgbuf  = (u16*)(ws);                               // N*256B   = 33,554,432 (hot)
    uint4* topiv  = (uint4*)(ws + (size_t)33554432);          // N*16     =  2,097,152
    int2*  slots  = (int2*)(ws + (size_t)35651584);           // N*8      =  1,048,576 (fallback)
    u32*   pc     = (u32*)(ws + (size_t)35651584);            // 16,384   (hot; aliases slots)
    u32*   bucket = (u32*)(ws + (size_t)36700160);            // 2N*4     =  1,048,576
    u32*   counts = (u32*)(ws + (size_t)37748736);            // 8 * 64B padded = 512B
    u32*   cursors = (u32*)(ws + (size_t)37749248);           // 8 * 64B padded = 512B
    u16*   wB1    = (u16*)(ws + (size_t)37749760);            // 131072 B (bf16 W1)
    u16*   wB2    = (u16*)(ws + (size_t)37880832);            // 131072 B (bf16 W2)
    const size_t WS_NEED = 38011904;

    (void)in_sizes; (void)n_in; (void)out_size;

    const bool use_mfma = (ws_size >= WS_NEED);

    if (use_mfma){
        k_proj   <<<512, 256, 0, stream>>>(qin, kin, vin, mem, Wq, Wk, Wv, fg,
                                           gW, gB, l1g, l1b, out1, out0, xgbuf,
                                           topiv, pc, 1);
        k_scatter<<<512, 256, 0, stream>>>(topiv, counts, cursors, pc,
                                           W1, W2, wB1, wB2, bucket, slots, out0, 1);
        k_expert_mfma<<<E_*1024, 256, 0, stream>>>(xgbuf, bucket, counts, topiv,
                                                   wB1, wB2, l2g, l2b, b2, out0);
    } else {
        k_zero   <<<1, 256, 0, stream>>>(counts);   // counts+cursors contiguous
        k_proj   <<<512, 256, 0, stream>>>(qin, kin, vin, mem, Wq, Wk, Wv, fg,
                                           gW, gB, l1g, l1b, out1, out0, xgbuf,
                                           topiv, pc, 0);
        k_gate   <<<NTOK/256, 256, 0, stream>>>(out0, gW, gB, l1g, l1b, topiv, counts, 0);
        k_scatter<<<NTOK/256, 256, 0, stream>>>(topiv, counts, cursors, pc,
                                                W1, W2, wB1, wB2, bucket, slots, out0, 0);
        k_expert <<<E_*512, 256, 0, stream>>>(out0, bucket, counts, W1, W2,
                                              l1g, l1b, l2g, l2b, b2, aout);
        k_combine<<<NTOK/16, 256, 0, stream>>>(aout, topiv, slots, out0);
    }
}

// Round 19
// 299.525 us; speedup vs baseline: 1.0554x; 1.0554x over previous
//
#include <hip/hip_runtime.h>
#include <stdint.h>

typedef unsigned short u16;
typedef unsigned int   u32;
typedef unsigned long long u64;
typedef __attribute__((ext_vector_type(8))) short short8;
typedef __attribute__((ext_vector_type(4))) short s16x4;
typedef __attribute__((ext_vector_type(4))) float f32x4;

#define B_    8
#define S_    1024
#define HID_  1024
#define NH_   16
#define HD_   64
#define E_    8
#define IDIM_ 128
#define NTOK  (B_*NH_*S_)   /* 131072 */

// padded-counter stride: one 64B cacheline per expert
#define CSTRIDE 16
// padded LDS row stride in floats (65 -> (row+d)%32 bank pattern, 2-way max)
#define XROW 65

// ---------- helpers ----------
__device__ __forceinline__ float bf2f(u16 u){ return __uint_as_float(((u32)u) << 16); }
__device__ __forceinline__ u16 f2bf(float f){
    u32 u = __float_as_uint(f);
    u32 r = u + 0x7fffu + ((u >> 16) & 1u);   // RNE
    return (u16)(r >> 16);
}
// 8 consecutive fp32 -> bf16 MFMA fragment (A or B operand)
__device__ __forceinline__ short8 frag8(const float* __restrict__ p){
    float4 a = *(const float4*)p;
    float4 b = *(const float4*)(p + 4);
    short8 r;
    r[0]=(short)f2bf(a.x); r[1]=(short)f2bf(a.y); r[2]=(short)f2bf(a.z); r[3]=(short)f2bf(a.w);
    r[4]=(short)f2bf(b.x); r[5]=(short)f2bf(b.y); r[6]=(short)f2bf(b.z); r[7]=(short)f2bf(b.w);
    return r;
}
// exact gelu (kept for scalar fallback path)
__device__ __forceinline__ float gelu_exact(float x){
    return 0.5f * x * (1.0f + erff(x * 0.70710678118654752f));
}
// tanh-form gelu: max abs err ~3e-4 vs exact; short dep chain, uses v_exp_f32
__device__ __forceinline__ float gelu_f(float x){
    float z = 1.5957691216057308f * (x + 0.044715f * x * x * x);   // 2*sqrt(2/pi)*(...)
    float e = __expf(z);                                            // exp(2*z_tanh)
    float t = 1.0f - 2.0f / (e + 1.0f);                             // tanh
    return 0.5f * x * (1.0f + t);
}

// ---------------- kernel 0: zero padded counters (fallback path only) ----------------
__global__ void k_zero(u32* c){
    c[threadIdx.x] = 0;   // launched with 256 threads
}

// ---------------- kernel 1 (fused): K/V/Q projections + memory cell + GATE + LN1/gelu ----------------
// Grid 512, 64 tokens/wave. writeXg=1: gate fused; xg rows stored in N-ORDER (contiguous
// 16KB/wave). Per-block expert histogram stored to pc[block][8] (plain stores, no atomics,
// no zeroing needed — fully overwritten each launch). Block j covers exactly n-chunk j.
// LESSONS (r13-r17): no tile time-sharing across barriers (32-f32 acc set spills);
// occupancy is grid-limited and NOT the lever; fp32 atomic combine is SLOWER than the
// bf16 aout round-trip + coalesced combine (r17: +16us). ~80us is k_proj's floor.
__global__ __launch_bounds__(256,2) void k_proj(
    const float* __restrict__ qin, const float* __restrict__ kin, const float* __restrict__ vin,
    const float* __restrict__ mem,
    const float* __restrict__ Wq, const float* __restrict__ Wk, const float* __restrict__ Wv,
    const float* __restrict__ fg,
    const float* __restrict__ gW, const float* __restrict__ gB,
    const float* __restrict__ l1g, const float* __restrict__ l1b,
    float* __restrict__ cur_out, float* __restrict__ out0,
    uint4* __restrict__ topiv, u32* __restrict__ pcount, int writeXg)
{
    __shared__ float sT[4][64*XROW];              // 66,560B: wave-private x tiles
    __shared__ float sGW[512], sGB[8];
    __shared__ float sG1[8*XROW], sB1g[8*XROW];   // stride-65: per-lane expert indexing conflict-free
    __shared__ u32 sWc1[4][8], sWc2[4][8];

    const int tid  = threadIdx.x;
    const int lane = tid & 63;
    const int wid  = tid >> 6;
    const int m    = lane & 15;
    const int kg   = lane >> 4;

    // stage gate/LN1 params (used only after the pre-epilogue barrier)
    for (int i = tid; i < 512; i += 256){
        sGW[i] = gW[i];
        const int e = i >> 6, d = i & 63;
        sG1[e*XROW+d] = l1g[i]; sB1g[e*XROW+d] = l1b[i];
    }
    if (tid < 8) sGB[tid] = gB[tid];

    const int slab  = blockIdx.x;                 // grid 512; slab == n-chunk index
    const int chunk = slab & 3, h = (slab >> 2) & 15, b = slab >> 6;
    const int tw    = chunk*256 + wid*64;         // 64 tokens per wave

    float* sW = &sT[wid][0];

    const float* kbase = kin + ((size_t)b*S_)*HID_ + h*64;
    const float* vbase = vin + ((size_t)b*S_)*HID_ + h*64;
    const float* qbase = qin + ((size_t)b*S_)*HID_ + h*64;

    f32x4 accK[4][4], accV[4][4];
    const f32x4 z = {0.f,0.f,0.f,0.f};
    #pragma unroll
    for (int i=0;i<4;i++){ accK[i][0]=z;accK[i][1]=z;accK[i][2]=z;accK[i][3]=z;
                           accV[i][0]=z;accV[i][1]=z;accV[i][2]=z;accV[i][3]=z; }

    // ---- K projection ----
    #pragma unroll
    for (int kk=0; kk<2; kk++){
        const int k0 = kk*32 + kg*8;
        short8 aF[4], bF[4];
        #pragma unroll
        for (int mt=0; mt<4; mt++) aF[mt] = frag8(kbase + (size_t)(tw + mt*16 + m)*HID_ + k0);
        #pragma unroll
        for (int ct=0; ct<4; ct++) bF[ct] = frag8(Wk + (ct*16 + m)*64 + k0);
        #pragma unroll
        for (int mt=0; mt<4; mt++)
            #pragma unroll
            for (int ct=0; ct<4; ct++)
                accK[mt][ct] = __builtin_amdgcn_mfma_f32_16x16x32_bf16(aF[mt], bF[ct], accK[mt][ct], 0,0,0);
    }
    // ---- V projection ----
    #pragma unroll
    for (int kk=0; kk<2; kk++){
        const int k0 = kk*32 + kg*8;
        short8 aF[4], bF[4];
        #pragma unroll
        for (int mt=0; mt<4; mt++) aF[mt] = frag8(vbase + (size_t)(tw + mt*16 + m)*HID_ + k0);
        #pragma unroll
        for (int ct=0; ct<4; ct++) bF[ct] = frag8(Wv + (ct*16 + m)*64 + k0);
        #pragma unroll
        for (int mt=0; mt<4; mt++)
            #pragma unroll
            for (int ct=0; ct<4; ct++)
                accV[mt][ct] = __builtin_amdgcn_mfma_f32_16x16x32_bf16(aF[mt], bF[ct], accV[mt][ct], 0,0,0);
    }

    const size_t nb = ((size_t)(b*NH_ + h)) << 10;
    float fgv[4];
    #pragma unroll
    for (int ct=0; ct<4; ct++) fgv[ct] = fg[ct*16 + m];

    // ---- epilogue 1: cell/cur -> out1; keep cur in accK ----
    #pragma unroll
    for (int mt=0; mt<4; mt++){
        #pragma unroll
        for (int r=0; r<4; r++){
            const int tok = tw + mt*16 + kg*4 + r;
            const size_t rowo = (nb + (size_t)tok)*64;
            #pragma unroll
            for (int ct=0; ct<4; ct++){
                const int d = ct*16 + m;
                const float kd = accK[mt][ct][r];
                const float vd = accV[mt][ct][r];
                const float f  = fgv[ct];
                const float mv = mem[rowo + d];
                const float cell = kd*vd + f*mv;
                const float cur  = (1.0f - f)*cell + f*mv;
                accK[mt][ct][r] = cur;            // keep for Q epilogue
                cur_out[rowo + d] = cur;
            }
        }
    }

    // ---- Q projection ----
    f32x4 accQ[4][4];
    #pragma unroll
    for (int i=0;i<4;i++){ accQ[i][0]=z;accQ[i][1]=z;accQ[i][2]=z;accQ[i][3]=z; }

    #pragma unroll
    for (int kk=0; kk<2; kk++){
        const int k0 = kk*32 + kg*8;
        short8 aF[4], bF[4];
        #pragma unroll
        for (int mt=0; mt<4; mt++) aF[mt] = frag8(qbase + (size_t)(tw + mt*16 + m)*HID_ + k0);
        #pragma unroll
        for (int ct=0; ct<4; ct++) bF[ct] = frag8(Wq + (ct*16 + m)*64 + k0);
        #pragma unroll
        for (int mt=0; mt<4; mt++)
            #pragma unroll
            for (int ct=0; ct<4; ct++)
                accQ[mt][ct] = __builtin_amdgcn_mfma_f32_16x16x32_bf16(aF[mt], bF[ct], accQ[mt][ct], 0,0,0);
    }

    if (!writeXg){
        // ---- fallback: fp32 x to out0 in pos-order (old k_gate computes gate later) ----
        #pragma unroll
        for (int mt=0; mt<4; mt++){
            #pragma unroll
            for (int r=0; r<4; r++){
                const int tok = tw + mt*16 + kg*4 + r;
                const size_t po = ((size_t)(b*S_ + tok)*NH_ + h)*64;
                #pragma unroll
                for (int ct=0; ct<4; ct++){
                    const int d = ct*16 + m;
                    out0[po + d] = accQ[mt][ct][r] * accK[mt][ct][r];
                }
            }
        }
        return;
    }

    __syncthreads();   // params staged; safe before first sGW use

    // ---- epilogue 2a: scatter x into wave tile (stride-65 rows) ----
    #pragma unroll
    for (int mt=0; mt<4; mt++){
        #pragma unroll
        for (int r=0; r<4; r++){
            const int trow = mt*16 + kg*4 + r;
            #pragma unroll
            for (int ct=0; ct<4; ct++){
                const int d = ct*16 + m;
                sW[trow*XROW + d] = accQ[mt][ct][r] * accK[mt][ct][r];
            }
        }
    }
    // in-wave DS ordering: lane's row reads below observe all wave writes above

    // ---- epilogue 2b: LANE = TOKEN — own row -> regs ((lane+d)%32 banks: 2-way) ----
    const int tok = tw + lane;
    const int n   = (int)(nb + tok);              // n-order index
    float rx[64];
    {
        const float* xr = &sW[lane*XROW];
        #pragma unroll
        for (int d = 0; d < 64; d++) rx[d] = xr[d];
    }

    // ---- epilogue 2c: logits + top-2 ----
    float lg[8];
    #pragma unroll
    for (int e = 0; e < 8; e++) lg[e] = sGB[e];
    float s0 = 0.f, s1 = 0.f;
    #pragma unroll
    for (int d = 0; d < 64; d++){
        const float xv = rx[d];
        s0 += xv; s1 += xv*xv;
        #pragma unroll
        for (int e = 0; e < 8; e++) lg[e] += sGW[e*64 + d] * xv;
    }

    int i1 = 0; float v1 = lg[0];
    #pragma unroll
    for (int e = 1; e < 8; e++){ if (lg[e] > v1){ v1 = lg[e]; i1 = e; } }
    int i2 = -1; float v2 = -3.0e38f;
    #pragma unroll
    for (int e = 0; e < 8; e++){ if (e != i1 && lg[e] > v2){ v2 = lg[e]; i2 = e; } }

    topiv[n] = make_uint4((u32)i1, (u32)i2, __float_as_uint(v1), __float_as_uint(v2));

    // per-wave expert histograms
    #pragma unroll
    for (int e = 0; e < 8; e++){
        u64 m1 = __ballot(i1 == e);
        u64 m2 = __ballot(i2 == e);
        if (lane == 0){ sWc1[wid][e] = (u32)__popcll(m1); sWc2[wid][e] = (u32)__popcll(m2); }
    }

    // ---- epilogue 2d: LN1 + gelu for both experts -> packed bf16 into OWN LDS row ----
    {
        const float mu = s0 * (1.0f/64.0f);
        const float rs = rsqrtf(s1 * (1.0f/64.0f) - mu*mu + 1e-5f);
        u32* xw = (u32*)&sW[lane*XROW];           // 64 u32 = 256B fits in 260B row
        #pragma unroll
        for (int half = 0; half < 2; half++){
            const int ee = half ? i2 : i1;
            const float* g1 = &sG1[ee*XROW];
            const float* b1 = &sB1g[ee*XROW];
            #pragma unroll
            for (int dp = 0; dp < 32; dp++){
                const float v0 = gelu_f((rx[2*dp+0] - mu)*rs*g1[2*dp+0] + b1[2*dp+0]);
                const float vb = gelu_f((rx[2*dp+1] - mu)*rs*g1[2*dp+1] + b1[2*dp+1]);
                xw[half*32 + dp] = (u32)f2bf(v0) | ((u32)f2bf(vb) << 16);
            }
        }
    }

    // ---- epilogue 2e: cooperative coalesced store — wave's 64 rows = contiguous 16KB ----
    {
        u16* xgbase = (u16*)out0 + ((nb + (size_t)tw) << 7);   // n-order, contiguous
        #pragma unroll
        for (int j = 0; j < 16; j++){
            const int idx = j*64 + lane;          // uint4 index in [0,1024)
            const int row = idx >> 4, dc = idx & 15;
            const u32* p = (const u32*)&sW[row*XROW] + dc*4;
            uint4 v; v.x = p[0]; v.y = p[1]; v.z = p[2]; v.w = p[3];
            ((uint4*)xgbase)[idx] = v;
        }
    }

    __syncthreads();   // sWc complete across the 4 waves
    if (tid < 8){
        u32 t = sWc1[0][tid] + sWc1[1][tid] + sWc1[2][tid] + sWc1[3][tid]
              + sWc2[0][tid] + sWc2[1][tid] + sWc2[2][tid] + sWc2[3][tid];
        pcount[blockIdx.x*8 + tid] = t;           // plain store, incl. zero
    }
}

// ---------------- kernel 3 (fallback only): gate + top-2 — LDS-staged streamer ----------------
__global__ __launch_bounds__(256,2) void k_gate(
    float* __restrict__ x_io, const float* __restrict__ gW, const float* __restrict__ gB,
    const float* __restrict__ l1g, const float* __restrict__ l1b,
    uint4* __restrict__ topiv, u32* __restrict__ counts, int writeXg)
{
    __shared__ float sX[256*XROW];               // 66.6KB staged rows
    __shared__ float sGW[512], sGB[8];
    __shared__ float sG1[8*XROW], sB1g[8*XROW];
    __shared__ u32 sWc[4][8];

    const int tid = threadIdx.x;
    for (int i = tid; i < 512; i += 256){
        sGW[i] = gW[i];
        const int e = i >> 6, d = i & 63;
        sG1[e*XROW+d] = l1g[i]; sB1g[e*XROW+d] = l1b[i];
    }
    if (tid < 8) sGB[tid] = gB[tid];

    const int rowBase = blockIdx.x * 256;
    const float* gsrc = x_io + ((size_t)rowBase << 6);
    #pragma unroll
    for (int j = 0; j < 16; j++){
        const int idx = j*256 + tid;
        const int row = idx >> 4, dc = idx & 15;
        float4 v = ((const float4*)gsrc)[idx];
        float* p = &sX[row*XROW + dc*4];
        p[0]=v.x; p[1]=v.y; p[2]=v.z; p[3]=v.w;
    }
    __syncthreads();

    const int pos = rowBase + tid;
    const int h  = pos & (NH_-1);
    const int bs = pos >> 4;
    const int s  = bs & (S_-1), b = bs >> 10;
    const int n  = ((b*NH_ + h) << 10) + s;

    float rx[64];
    {
        const float* xr = &sX[tid*XROW];
        #pragma unroll
        for (int d = 0; d < 64; d++) rx[d] = xr[d];
    }

    float lg[8];
    #pragma unroll
    for (int e = 0; e < 8; e++) lg[e] = sGB[e];
    float s0 = 0.f, s1 = 0.f;
    #pragma unroll
    for (int d = 0; d < 64; d++){
        const float xv = rx[d];
        s0 += xv; s1 += xv*xv;
        #pragma unroll
        for (int e = 0; e < 8; e++) lg[e] += sGW[e*64 + d] * xv;
    }

    int i1 = 0; float v1 = lg[0];
    #pragma unroll
    for (int e = 1; e < 8; e++){ if (lg[e] > v1){ v1 = lg[e]; i1 = e; } }
    int i2 = -1; float v2 = -3.0e38f;
    #pragma unroll
    for (int e = 0; e < 8; e++){ if (e != i1 && lg[e] > v2){ v2 = lg[e]; i2 = e; } }

    topiv[n] = make_uint4((u32)i1, (u32)i2, __float_as_uint(v1), __float_as_uint(v2));

    {
        const int lane = tid & 63;
        const int w    = tid >> 6;
        #pragma unroll
        for (int e = 0; e < 8; e++){
            u64 m1 = __ballot(i1 == e);
            u64 m2 = __ballot(i2 == e);
            if (lane == 0) sWc[w][e] = (u32)(__popcll(m1) + __popcll(m2));
        }
    }
    __syncthreads();

    if (tid < 8){
        u32 t = sWc[0][tid] + sWc[1][tid] + sWc[2][tid] + sWc[3][tid];
        if (t) atomicAdd(&counts[tid*CSTRIDE], t);
    }
    (void)writeXg;
}

// ---------------- kernel 4: scatter + (MFMA path) weight conversion + deterministic prefix ----------------
__global__ __launch_bounds__(256,2) void k_scatter(
    const uint4* __restrict__ topiv, u32* __restrict__ counts, u32* __restrict__ cursors,
    const u32* __restrict__ pc,
    const float* __restrict__ W1, const float* __restrict__ W2,
    u16* __restrict__ wB1, u16* __restrict__ wB2,
    u32* __restrict__ bucket, int2* __restrict__ slots, int useMfma)
{
    __shared__ u32 sC1[4][8], sC2[4][8];   // per-wave counts
    __shared__ u32 sB1[4][8], sB2w[4][8];  // per-wave slot bases (absolute)
    __shared__ u32 pcL[4096];              // 16KB pc table
    __shared__ u32 sTot[8], sBase[8];

    const int tid = threadIdx.x;
    const int j   = blockIdx.x;
    const int n   = j*256 + tid;

    if (useMfma){
        // weight conversion: exactly one element per thread across the grid
        if (n < 65536) wB1[n] = f2bf(W1[n]);
        else           wB2[n - 65536] = f2bf(W2[n - 65536]);
        for (int i = tid; i < 4096; i += 256) pcL[i] = pc[i];
    }

    uint4 t = topiv[n];
    const int i1 = (int)t.x, i2 = (int)t.y;

    const int lane = tid & 63;
    const int w    = tid >> 6;
    const u64 low = (1ull << lane) - 1ull;

    u64 myM1 = 0, myM2 = 0;
    #pragma unroll
    for (int e = 0; e < 8; e++){
        u64 m1 = __ballot(i1 == e);
        u64 m2 = __ballot(i2 == e);
        if (i1 == e) myM1 = m1;
        if (i2 == e) myM2 = m2;
        if (lane == 0){ sC1[w][e] = (u32)__popcll(m1); sC2[w][e] = (u32)__popcll(m2); }
    }
    __syncthreads();

    if (useMfma){
        if (tid < 8){
            const int e = tid;
            u32 tot = 0, base = 0;
            for (int i = 0; i < 512; i++){
                const u32 c = pcL[i*8 + e];
                tot += c;
                if (i < j) base += c;
            }
            sTot[e] = tot; sBase[e] = base;
            if (j == 0) counts[e*CSTRIDE] = tot;   // publish for expert/combine
        }
        __syncthreads();
        if (tid < 8){
            const int e = tid;
            u32 off = 0;
            #pragma unroll
            for (int ee = 0; ee < 8; ee++){ if (ee < e) off += sTot[ee]; }
            u32 run = off + sBase[e];
            #pragma unroll
            for (int ww = 0; ww < 4; ww++){
                sB1[ww][e] = run; run += sC1[ww][e];
                sB2w[ww][e] = run; run += sC2[ww][e];
            }
        }
        __syncthreads();
    } else {
        int off[8]; int acc = 0;
        #pragma unroll
        for (int e = 0; e < 8; e++){ off[e] = acc; acc += (int)counts[e*CSTRIDE]; }
        if (tid < 8){
            const int e = tid;
            u32 tot = 0;
            #pragma unroll
            for (int ww = 0; ww < 4; ww++) tot += sC1[ww][e] + sC2[ww][e];
            u32 base = tot ? atomicAdd(&cursors[e*CSTRIDE], tot) : 0;
            u32 run = (u32)off[e] + base;
            #pragma unroll
            for (int ww = 0; ww < 4; ww++){
                sB1[ww][e] = run; run += sC1[ww][e];
                sB2w[ww][e] = run; run += sC2[ww][e];
            }
        }
        __syncthreads();
    }

    const int slot1 = (int)sB1[w][i1] + (int)__popcll(myM1 & low);
    const int slot2 = (int)sB2w[w][i2] + (int)__popcll(myM2 & low);

    bucket[slot1] = ((u32)n << 1);
    bucket[slot2] = ((u32)n << 1) | 1u;
    slots[n] = make_int2(slot1, slot2);
}

// ---------------- kernel 5 (MFMA): wave-independent expert FFN — A-rows pre-staged bf16 ----------------
__global__ __launch_bounds__(256,4) void k_expert_mfma(
    const float* __restrict__ x_src, const u32* __restrict__ bucket, const u32* __restrict__ counts,
    const u16* __restrict__ wB1, const u16* __restrict__ wB2,
    const float* __restrict__ l2g, const float* __restrict__ l2b,
    const float* __restrict__ b2,  u16* __restrict__ aout)
{
    const int e = blockIdx.x >> 10;
    const int c = blockIdx.x & 1023;
    const int cnt = (int)counts[e*CSTRIDE];
    const int aBase = c * 128;
    if (aBase >= cnt) return;     // block-uniform, before any barrier

    int off = 0;
    #pragma unroll
    for (int ee = 0; ee < 8; ee++){ if (ee < e) off += (int)counts[ee*CSTRIDE]; }

    __shared__ __align__(16) u16 sH[4][32*128];   // 8KB per wave (reused for out staging)
    __shared__ float sL2g[128], sL2b[128], sB2[64];

    const int tid = threadIdx.x;
    if (tid < 128){ sL2g[tid] = l2g[e*128+tid]; sL2b[tid] = l2b[e*128+tid]; }
    else if (tid < 192){ sB2[tid-128] = b2[e*64 + tid-128]; }
    __syncthreads();   // only barrier in the kernel

    const int lane = tid & 63;
    const int w    = tid >> 6;
    const int m    = lane & 15;
    const int kg   = lane >> 4;
    const int tb   = aBase + w*32;          // wave token base
    char* sHw = (char*)(&sH[w][0]);         // wave-private 8KB

    // ---- phase A: gather pre-staged bf16 A-rows (xg half-rows inside out0, n-order) ----
    const u16* xg = (const u16*)x_src;
    short8 aF[2][2];   // [tile][kk]
    #pragma unroll
    for (int t = 0; t < 2; t++){
        int a = tb + t*16 + m; if (a > cnt-1) a = cnt-1;
        const u32 bv = bucket[off + a];
        const u16* rp = xg + (((size_t)(bv >> 1)) << 7) + (bv & 1u)*64;
        aF[t][0] = *(const short8*)(rp + kg*8);
        aF[t][1] = *(const short8*)(rp + 32 + kg*8);
    }

    // ---- GEMM1: H[32x128] = A1[32x64] @ W1^T ----
    const f32x4 z = {0.f,0.f,0.f,0.f};
    f32x4 acc1[2][8];
    #pragma unroll
    for (int t = 0; t < 2; t++)
        #pragma unroll
        for (int ct = 0; ct < 8; ct++) acc1[t][ct] = z;

    const u16* wB1e = wB1 + e*8192;
    #pragma unroll
    for (int kk = 0; kk < 2; kk++){
        const int k0 = kk*32 + kg*8;
        short8 bF[8];
        #pragma unroll
        for (int ct = 0; ct < 8; ct++)
            bF[ct] = *(const short8*)(wB1e + (ct*16 + m)*64 + k0);
        #pragma unroll
        for (int t = 0; t < 2; t++)
            #pragma unroll
            for (int ct = 0; ct < 8; ct++)
                acc1[t][ct] = __builtin_amdgcn_mfma_f32_16x16x32_bf16(aF[t][kk], bF[ct], acc1[t][ct], 0,0,0);
    }

    // ---- LN2 (reduce over m-lanes) + gelu -> wave-private sH (swizzled) ----
    #pragma unroll
    for (int t = 0; t < 2; t++){
        #pragma unroll
        for (int r = 0; r < 4; r++){
            float p0 = 0.f, p1 = 0.f;
            #pragma unroll
            for (int ct = 0; ct < 8; ct++){ float v = acc1[t][ct][r]; p0 += v; p1 += v*v; }
            #pragma unroll
            for (int msk = 1; msk < 16; msk <<= 1){
                p0 += __shfl_xor(p0, msk);
                p1 += __shfl_xor(p1, msk);
            }
            const float mu = p0 * (1.0f/128.0f);
            const float rs = rsqrtf(p1 * (1.0f/128.0f) - mu*mu + 1e-5f);
            const int row = t*16 + kg*4 + r;           // local row 0..31
            #pragma unroll
            for (int ct = 0; ct < 8; ct++){
                const int col = ct*16 + m;
                *(u16*)(sHw + (((row<<8) + (col<<1)) ^ ((row&7)<<4)))
                    = f2bf(gelu_f((acc1[t][ct][r] - mu)*rs*sL2g[col] + sL2b[col]));
            }
        }
    }
    // DS ops are in-order within a wave: reads below observe the writes above.

    // ---- GEMM2: OUT[32x64] = H[32x128] @ W2^T ----
    f32x4 acc2[2][4];
    #pragma unroll
    for (int t = 0; t < 2; t++)
        #pragma unroll
        for (int ct = 0; ct < 4; ct++) acc2[t][ct] = z;

    const u16* wB2e = wB2 + e*8192;
    #pragma unroll
    for (int kk = 0; kk < 4; kk++){
        const int k0 = kk*32 + kg*8;
        short8 aF2[2], bF2[4];
        #pragma unroll
        for (int t = 0; t < 2; t++){
            const int row = t*16 + m;
            aF2[t] = *(const short8*)(sHw + (((row<<8) + (k0<<1)) ^ ((row&7)<<4)));
        }
        #pragma unroll
        for (int ct = 0; ct < 4; ct++)
            bF2[ct] = *(const short8*)(wB2e + (ct*16 + m)*128 + k0);
        #pragma unroll
        for (int t = 0; t < 2; t++)
            #pragma unroll
            for (int ct = 0; ct < 4; ct++)
                acc2[t][ct] = __builtin_amdgcn_mfma_f32_16x16x32_bf16(aF2[t], bF2[ct], acc2[t][ct], 0,0,0);
    }

    // ---- epilogue: +b2 -> bf16 -> wave LDS out tile (row stride 128B, same swizzle) ----
    #pragma unroll
    for (int t = 0; t < 2; t++){
        #pragma unroll
        for (int r = 0; r < 4; r++){
            const int row = t*16 + kg*4 + r;
            #pragma unroll
            for (int ct = 0; ct < 4; ct++){
                const int col = ct*16 + m;
                *(u16*)(sHw + (((row<<7) + (col<<1)) ^ ((row&7)<<4)))
                    = f2bf(acc2[t][ct][r] + sB2[col]);
            }
        }
    }

    // ---- coalesced 16B stores (wave's aout rows contiguous) ----
    #pragma unroll
    for (int it = 0; it < 4; it++){
        const int idx = it*64 + lane;          // 0..255
        const int row = idx >> 3, qq = idx & 7;
        if (tb + row < cnt){
            uint4 v = *(const uint4*)(sHw + (((row<<7) + (qq<<4)) ^ ((row&7)<<4)));
            *(uint4*)(aout + ((size_t)(off + tb + row) << 6) + qq*8) = v;
        }
    }
}

// ---------------- kernel 5 (fallback, scalar — used only if ws too small; raw x intact) ----------------
__global__ __launch_bounds__(256,2) void k_expert(
    const float* __restrict__ x_src, const u32* __restrict__ bucket, const u32* __restrict__ counts,
    const float* __restrict__ W1,  const float* __restrict__ W2,
    const float* __restrict__ l1g, const float* __restrict__ l1b,
    const float* __restrict__ l2g, const float* __restrict__ l2b,
    const float* __restrict__ b2,  u16* __restrict__ aout)
{
    const int e = blockIdx.x >> 9;
    const int c = blockIdx.x & 511;
    const int cnt = (int)counts[e*CSTRIDE];
    const int aBase = c * 256;
    if (aBase >= cnt) return;

    int off = 0;
    for (int ee = 0; ee < 8; ee++){ if (ee < e) off += (int)counts[ee*CSTRIDE]; }

    __shared__ float sW1[8192];
    __shared__ float sW2T[128*68];
    __shared__ float sL1g[64], sL1b[64], sL2g[128], sL2b[128], sB2[64];
    const int tid = threadIdx.x;
    for (int i = tid; i < 8192; i += 256){
        sW1[i] = W1[e*8192 + i];
        int d = i >> 7, j = i & 127;
        sW2T[j*68 + d] = W2[e*8192 + i];
    }
    if (tid < 64){ sL1g[tid] = l1g[e*64+tid]; sL1b[tid] = l1b[e*64+tid]; sB2[tid] = b2[e*64+tid]; }
    if (tid < 128){ sL2g[tid] = l2g[e*128+tid]; sL2b[tid] = l2b[e*128+tid]; }
    __syncthreads();

    const int a = aBase + tid;
    if (a >= cnt) return;
    const u32 nv = bucket[off + a] >> 1;          // n-order index
    const int s = (int)(nv & (S_-1));
    const int h = (int)((nv >> 10) & (NH_-1));
    const int b = (int)(nv >> 14);
    const u32 pos32 = (u32)((b*S_ + s)*NH_ + h);

    float g[64];
    #pragma unroll
    for (int i = 0; i < 16; i++){
        float4 t = ((const float4*)(x_src + (size_t)pos32*64))[i];
        g[i*4+0]=t.x; g[i*4+1]=t.y; g[i*4+2]=t.z; g[i*4+3]=t.w;
    }

    float s0 = 0.f, s1 = 0.f;
    #pragma unroll
    for (int d = 0; d < 64; d++){ s0 += g[d]; s1 += g[d]*g[d]; }
    float m  = s0 * (1.0f/64.0f);
    float va = s1 * (1.0f/64.0f) - m*m;
    float rs = rsqrtf(va + 1e-5f);
    #pragma unroll
    for (int d = 0; d < 64; d++) g[d] = gelu_exact((g[d]-m)*rs*sL1g[d] + sL1b[d]);

    u32 hpk[64];
    float hs = 0.f, hs2 = 0.f;
    for (int jp = 0; jp < 64; jp++){
        float h0, h1;
        {
            float a0=0.f,a1=0.f,a2=0.f,a3=0.f;
            const float4* w4 = (const float4*)&sW1[(2*jp)*64];
            #pragma unroll
            for (int i = 0; i < 16; i++){
                float4 ww = w4[i];
                a0 += ww.x*g[i*4+0]; a1 += ww.y*g[i*4+1]; a2 += ww.z*g[i*4+2]; a3 += ww.w*g[i*4+3];
            }
            h0 = (a0+a1)+(a2+a3);
        }
        {
            float a0=0.f,a1=0.f,a2=0.f,a3=0.f;
            const float4* w4 = (const float4*)&sW1[(2*jp+1)*64];
            #pragma unroll
            for (int i = 0; i < 16; i++){
                float4 ww = w4[i];
                a0 += ww.x*g[i*4+0]; a1 += ww.y*g[i*4+1]; a2 += ww.z*g[i*4+2]; a3 += ww.w*g[i*4+3];
            }
            h1 = (a0+a1)+(a2+a3);
        }
        hs += h0 + h1; hs2 += h0*h0 + h1*h1;
        hpk[jp] = (u32)f2bf(h0) | ((u32)f2bf(h1) << 16);
    }
    float m2  = hs  * (1.0f/128.0f);
    float va2 = hs2 * (1.0f/128.0f) - m2*m2;
    float rs2 = rsqrtf(va2 + 1e-5f);

    float acc[64];
    #pragma unroll
    for (int d = 0; d < 64; d++) acc[d] = sB2[d];
    for (int j = 0; j < 128; j++){
        float hj = bf2f((u16)((j & 1) ? (hpk[j>>1] >> 16) : (hpk[j>>1] & 0xffffu)));
        float gh = gelu_exact((hj - m2)*rs2*sL2g[j] + sL2b[j]);
        const float4* w2t = (const float4*)&sW2T[j*68];
        #pragma unroll
        for (int d4 = 0; d4 < 16; d4++){
            float4 w = w2t[d4];
            acc[d4*4+0] += gh * w.x;
            acc[d4*4+1] += gh * w.y;
            acc[d4*4+2] += gh * w.z;
            acc[d4*4+3] += gh * w.w;
        }
    }

    u16* op = aout + (size_t)(off + a) * 64;
    #pragma unroll
    for (int dc = 0; dc < 8; dc++){
        uint4 o;
        o.x = (u32)f2bf(acc[dc*8+0]) | ((u32)f2bf(acc[dc*8+1]) << 16);
        o.y = (u32)f2bf(acc[dc*8+2]) | ((u32)f2bf(acc[dc*8+3]) << 16);
        o.z = (u32)f2bf(acc[dc*8+4]) | ((u32)f2bf(acc[dc*8+5]) << 16);
        o.w = (u32)f2bf(acc[dc*8+6]) | ((u32)f2bf(acc[dc*8+7]) << 16);
        ((uint4*)op)[dc] = o;
    }
}

// ---------------- kernel 6: combine top-2 expert outputs -> out0 (overwrites x/xg) ----------------
__global__ __launch_bounds__(256,4) void k_combine(
    const u16* __restrict__ aout, const uint4* __restrict__ topiv,
    const int2* __restrict__ slots, float* __restrict__ out0)
{
    const int tid = threadIdx.x;
    const int p   = blockIdx.x*16 + (tid >> 4);
    const int cq  = tid & 15;

    const int h  = p & (NH_-1);
    const int bs = p >> 4;
    const int b  = bs >> 10, s = bs & (S_-1);
    const int n  = ((b*NH_ + h) << 10) + s;

    uint4 t = topiv[n];
    float w1 = __uint_as_float(t.z), w2 = __uint_as_float(t.w);
    int2 sl = slots[n];

    uint2 ua = *(const uint2*)(aout + (size_t)sl.x*64 + cq*4);
    uint2 ub = *(const uint2*)(aout + (size_t)sl.y*64 + cq*4);

    float4 o;
    o.x = w1*bf2f((u16)(ua.x & 0xffffu)) + w2*bf2f((u16)(ub.x & 0xffffu));
    o.y = w1*bf2f((u16)(ua.x >> 16))     + w2*bf2f((u16)(ub.x >> 16));
    o.z = w1*bf2f((u16)(ua.y & 0xffffu)) + w2*bf2f((u16)(ub.y & 0xffffu));
    o.w = w1*bf2f((u16)(ua.y >> 16))     + w2*bf2f((u16)(ub.y >> 16));
    *(float4*)(out0 + (size_t)p*64 + cq*4) = o;
}

// ---------------- launch ----------------
extern "C" void kernel_launch(void* const* d_in, const int* in_sizes, int n_in,
                              void* d_out, int out_size, void* d_ws, size_t ws_size,
                              hipStream_t stream)
{
    const float* qin = (const float*)d_in[0];
    const float* kin = (const float*)d_in[1];
    const float* vin = (const float*)d_in[2];
    const float* mem = (const float*)d_in[3];
    const float* Wq  = (const float*)d_in[4];
    const float* Wk  = (const float*)d_in[5];
    const float* Wv  = (const float*)d_in[6];
    const float* fg  = (const float*)d_in[7];
    const float* gW  = (const float*)d_in[8];
    const float* gB  = (const float*)d_in[9];
    const float* l1g = (const float*)d_in[10];
    const float* l1b = (const float*)d_in[11];
    const float* W1  = (const float*)d_in[12];
    const float* l2g = (const float*)d_in[13];
    const float* l2b = (const float*)d_in[14];
    const float* W2  = (const float*)d_in[15];
    const float* b2  = (const float*)d_in[16];

    float* out0 = (float*)d_out;                    // token_mixing [B,S,NH*HD]
    float* out1 = out0 + (size_t)NTOK * 64;         // current_memorys [B,NH,S,HD]

    // ws layout (WS_NEED unchanged; pc table aliases the first 16KB of aout — lifetimes
    // disjoint: pc lives proj->scatter, aout lives expert->combine)
    char* ws = (char*)d_ws;
    u16*   aout   = (u16*)(ws);                               // 2N*64*2  = 33,554,432
    u32*   pc     = (u32*)(ws);                               // 512*8*4  = 16,384 (aliases aout)
    uint4* topiv  = (uint4*)(ws + (size_t)33554432);          // N*16     =  2,097,152
    int2*  slots  = (int2*)(ws + (size_t)35651584);           // N*8      =  1,048,576
    u32*   bucket = (u32*)(ws + (size_t)36700160);            // 2N*4     =  1,048,576
    u32*   counts = (u32*)(ws + (size_t)37748736);            // 8 * 64B padded = 512B
    u32*   cursors = (u32*)(ws + (size_t)37749248);           // 8 * 64B padded = 512B
    u16*   wB1    = (u16*)(ws + (size_t)37749760);            // 131072 B (bf16 W1)
    u16*   wB2    = (u16*)(ws + (size_t)37880832);            // 131072 B (bf16 W2)
    const size_t WS_NEED = 38011904;

    (void)in_sizes; (void)n_in; (void)out_size;

    const bool use_mfma = (ws_size >= WS_NEED);

    if (use_mfma){
        k_proj   <<<512, 256, 0, stream>>>(qin, kin, vin, mem, Wq, Wk, Wv, fg,
                                           gW, gB, l1g, l1b, out1, out0,
                                           topiv, pc, 1);
        k_scatter<<<512, 256, 0, stream>>>(topiv, counts, cursors, pc,
                                           W1, W2, wB1, wB2, bucket, slots, 1);
        k_expert_mfma<<<E_*1024, 256, 0, stream>>>(out0, bucket, counts, wB1, wB2,
                                                   l2g, l2b, b2, aout);
        k_combine<<<NTOK/16, 256, 0, stream>>>(aout, topiv, slots, out0);
    } else {
        k_zero   <<<1, 256, 0, stream>>>(counts);   // counts+cursors contiguous
        k_proj   <<<512, 256, 0, stream>>>(qin, kin, vin, mem, Wq, Wk, Wv, fg,
                                           gW, gB, l1g, l1b, out1, out0,
                                           topiv, pc, 0);
        k_gate   <<<NTOK/256, 256, 0, stream>>>(out0, gW, gB, l1g, l1b, topiv, counts, 0);
        k_scatter<<<NTOK/256, 256, 0, stream>>>(topiv, counts, cursors, pc,
                                                W1, W2, wB1, wB2, bucket, slots, 0);
        k_expert <<<E_*512, 256, 0, stream>>>(out0, bucket, counts, W1, W2,
                                              l1g, l1b, l2g, l2b, b2, aout);
        k_combine<<<NTOK/16, 256, 0, stream>>>(aout, topiv, slots, out0);
    }
}